// Round 1
// baseline (271.893 us; speedup 1.0000x reference)
//
#include <hip/hip_runtime.h>

#define EDIM 300
#define NB   128
#define NQ   16
#define ND   1024
#define NK   11

// ---------------- Kernel 1: normalize query embeddings into ws ----------------
// grid = B*Q blocks of 64 (one wave per query row)
__global__ void qnorm_kernel(const int* __restrict__ qtoks,
                             const float* __restrict__ emb,
                             float* __restrict__ qn) {
    int row  = blockIdx.x;          // b*16 + q
    int lane = threadIdx.x;         // 0..63
    int tok  = qtoks[row];
    const float* src = emb + (long)tok * EDIM;
    float v[5];
    float ssq = 0.f;
#pragma unroll
    for (int j = 0; j < 5; ++j) {
        int e = lane + 64 * j;
        v[j] = (e < EDIM) ? src[e] : 0.f;
        ssq += v[j] * v[j];
    }
#pragma unroll
    for (int off = 32; off >= 1; off >>= 1)
        ssq += __shfl_xor(ssq, off, 64);
    float rn = 1.0f / (sqrtf(ssq) + 1e-9f);
#pragma unroll
    for (int j = 0; j < 5; ++j) {
        int e = lane + 64 * j;
        if (e < EDIM) qn[(long)row * EDIM + e] = v[j] * rn;
    }
}

// ---------------- Kernel 2: fused sim + RBF-bank partial sums ----------------
// grid = B*4 blocks of 256; block handles (b, 256 docs). Thread owns one doc:
// streams raw row (float4), accumulates 16 fp32 dots vs LDS q-rows + own ||d||^2.
// Then LDS-transpose sims and have 176 threads own one (k,q) pair each.
__global__ __launch_bounds__(256) void knrm_main(
    const int*   __restrict__ dtoks,
    const float* __restrict__ emb,
    const float* __restrict__ qn,
    const float* __restrict__ mus,
    const float* __restrict__ sigmas,
    float*       __restrict__ acc) {
    __shared__ __align__(16) float qn_s[NQ * EDIM];   // 19.2 KB
    __shared__ float sim_s[256 * 17];                 // 17.4 KB (pad 16->17: conflict-free)

    int blk    = blockIdx.x;
    int b      = blk >> 2;
    int dchunk = blk & 3;
    int tid    = threadIdx.x;

    for (int i = tid; i < NQ * EDIM; i += 256)
        qn_s[i] = qn[(long)b * NQ * EDIM + i];
    __syncthreads();

    int d   = dchunk * 256 + tid;
    int tok = dtoks[b * ND + d];
    const float4* rowp = (const float4*)(emb + (long)tok * EDIM);  // 1200B rows: 16B aligned

    float sims[NQ];
#pragma unroll
    for (int q = 0; q < NQ; ++q) sims[q] = 0.f;
    float ssq = 0.f;

    for (int c = 0; c < EDIM / 4; ++c) {
        float4 dv = rowp[c];
        ssq += dv.x * dv.x + dv.y * dv.y + dv.z * dv.z + dv.w * dv.w;
#pragma unroll
        for (int q = 0; q < NQ; ++q) {
            const float4 qv = *(const float4*)&qn_s[q * EDIM + c * 4];  // broadcast read
            sims[q] += qv.x * dv.x + qv.y * dv.y + qv.z * dv.z + qv.w * dv.w;
        }
    }
    // sim = dot(qn, d_raw) / (||d_raw|| + eps); pad docs (tok 0) -> all-zero row -> sim 0
    float rn = 1.0f / (sqrtf(ssq) + 1e-9f);
#pragma unroll
    for (int q = 0; q < NQ; ++q) sim_s[tid * 17 + q] = sims[q] * rn;
    __syncthreads();

    if (tid < NK * NQ) {
        int q = tid & 15;
        int k = tid >> 4;
        float mu = mus[k];
        float sg = sigmas[k];
        float cc = -0.5f / (sg * sg);
        float a  = 0.f;
        for (int dd = 0; dd < 256; ++dd) {
            float s    = sim_s[dd * 17 + q];
            float diff = s - mu;
            a += __expf(cc * diff * diff);
        }
        atomicAdd(&acc[b * (NK * NQ) + tid], a);   // acc[b][k][q], tid == k*16+q
    }
}

// ---------------- Kernel 3: masked log-sum over q, FC ----------------
// grid = 2 blocks of 64, thread = b
__global__ void knrm_final(const float* __restrict__ acc,
                           const int*   __restrict__ qtoks,
                           const float* __restrict__ fc_w,
                           const float* __restrict__ fc_b,
                           float*       __restrict__ out) {
    int b = blockIdx.x * 64 + threadIdx.x;
    if (b >= NB) return;
    float score = fc_b[0];
    for (int k = 0; k < NK; ++k) {
        float rk = 0.f;
        for (int q = 0; q < NQ; ++q) {
            if (qtoks[b * NQ + q] != 0)
                rk += logf(acc[b * NK * NQ + k * NQ + q] + 1e-6f);
        }
        score += rk * fc_w[k];
    }
    out[b] = score;
}

extern "C" void kernel_launch(void* const* d_in, const int* in_sizes, int n_in,
                              void* d_out, int out_size, void* d_ws, size_t ws_size,
                              hipStream_t stream) {
    const int*   doctoks   = (const int*)  d_in[0];   // [128,1024]
    const int*   querytoks = (const int*)  d_in[1];   // [128,16]
    // d_in[2] = query_idf: unused by the reference
    const float* emb       = (const float*)d_in[3];   // [100000,300]
    const float* mus       = (const float*)d_in[4];   // [11]
    const float* sigmas    = (const float*)d_in[5];   // [11]
    const float* fc_w      = (const float*)d_in[6];   // [1,11]
    const float* fc_b      = (const float*)d_in[7];   // [1]
    float* out = (float*)d_out;                        // [128]

    float* qn  = (float*)d_ws;                         // 2048*300 floats
    float* acc = qn + (long)NB * NQ * EDIM;            // 128*176 floats

    hipMemsetAsync(acc, 0, (size_t)NB * NK * NQ * sizeof(float), stream);
    qnorm_kernel<<<NB * NQ, 64, 0, stream>>>(querytoks, emb, qn);
    knrm_main<<<NB * 4, 256, 0, stream>>>(doctoks, emb, qn, mus, sigmas, acc);
    knrm_final<<<2, 64, 0, stream>>>(acc, querytoks, fc_w, fc_b, out);
}